// Round 18
// baseline (126.919 us; speedup 1.0000x reference)
//
#include <hip/hip_runtime.h>
#include <hip/hip_bf16.h>

#define NN 50000
#define FF 128
#define UU 128
#define NREL 8
#define NE 60000
#define NKEY (NREL * NN)        // 400000
#define NET (NREL * NE)         // 480000

typedef __attribute__((ext_vector_type(8))) short bf16x8;
typedef __attribute__((ext_vector_type(4))) float f32x4;

// ---------------- fused prep + build ----------------
// prep: X->bf16; W->fragment layout (for (m,c,s), a 1KB block at
// ((m*8+c)*4+s)*512 ushorts; lane (ag*16+al) holds 8 bf16 of
// W_m[k=s*32+ag*8+j][col=c*16+al]).
// build: per-(rel,dst) linked list via atomicExch (head pre-set to -1 by the
// stream-ordered memset); rec[i] = {src, w_bits, prev, pad}.

__global__ __launch_bounds__(256) void prepbuild_kernel(
    const float* __restrict__ X, const float* __restrict__ Wself,
    const float* __restrict__ Wrel, const int* __restrict__ esrc,
    const int* __restrict__ edst, const float* __restrict__ ew,
    ushort* __restrict__ Xb, ushort* __restrict__ Wf,
    int* __restrict__ head, int4* __restrict__ rec)
{
    int i = blockIdx.x * 256 + threadIdx.x;
    if (i < NN * FF / 4) {                      // X -> bf16
        float4 v = ((const float4*)X)[i];
        union { __hip_bfloat162 h[2]; uint2 u; } p;
        p.h[0] = __float22bfloat162_rn(make_float2(v.x, v.y));
        p.h[1] = __float22bfloat162_rn(make_float2(v.z, v.w));
        ((uint2*)Xb)[i] = p.u;
    }
    if (i < NET) {                              // linked-list build
        int key = (i / NE) * NN + edst[i];      // const divisor -> magic mul
        int prev = atomicExch(&head[key], i);
        rec[i] = make_int4(esrc[i], __float_as_int(ew[i]), prev, 0);
    }
    if (i < 9 * FF * UU) {                      // W -> fragment layout
        int m = i >> 14, k = (i >> 7) & 127, col = i & 127;
        int c = col >> 4, al = col & 15;
        int s = k >> 5, ag = (k >> 3) & 3, j = k & 7;
        float v = (m == 0) ? Wself[i] : Wrel[i - FF * UU];
        __hip_bfloat16 h = __float2bfloat16(v);
        Wf[((m * 8 + c) * 4 + s) * 512 + (ag * 16 + al) * 8 + j] = *(ushort*)&h;
    }
}

// ---------------- pass 1: aggregation (r15 walker + empty-key store skip) -------

#define AGG_L1R(i) int4 r##i = make_int4(0, 0, 0, 0); \
    if (e##i >= 0) r##i = rec[e##i];
#define AGG_L1X(i) uint x##i = 0u; \
    if (e##i >= 0) x##i = *(const uint*)(Xb + (size_t)r##i.x * FF + 2 * l);
#define AGG_L2R(i) int f##i = (e##i >= 0) ? r##i.z : -1; \
    int4 s##i = make_int4(0, 0, 0, 0); \
    if (f##i >= 0) s##i = rec[f##i];
#define AGG_L1A(i) if (e##i >= 0) { \
        float wgt = __int_as_float(r##i.y); \
        ax##i = fmaf(__uint_as_float(x##i << 16), wgt, ax##i); \
        ay##i = fmaf(__uint_as_float(x##i & 0xffff0000u), wgt, ay##i); }
#define AGG_L2X(i) uint y##i = 0u; \
    if (f##i >= 0) y##i = *(const uint*)(Xb + (size_t)s##i.x * FF + 2 * l);
#define AGG_L2A(i) if (f##i >= 0) { \
        float wgt = __int_as_float(s##i.y); \
        ax##i = fmaf(__uint_as_float(y##i << 16), wgt, ax##i); \
        ay##i = fmaf(__uint_as_float(y##i & 0xffff0000u), wgt, ay##i); \
        e##i = s##i.z; \
        if (e##i >= 0) r##i = rec[e##i]; \
    } else e##i = -1;

#define AGG_WALK(e, r, ax, ay)                                              \
    while (e >= 0) {                                                        \
        float w = __int_as_float(r.y);                                      \
        uint x = *(const uint*)(Xb + (size_t)r.x * FF + 2 * l);             \
        e = r.z;                                                            \
        if (e >= 0) r = rec[e];                                             \
        ax = fmaf(__uint_as_float(x << 16), w, ax);                         \
        ay = fmaf(__uint_as_float(x & 0xffff0000u), w, ay);                 \
    }

#define AGG_ST(i) { \
        __hip_bfloat162 hh = __float22bfloat162_rn(make_float2(ax##i, ay##i)); \
        *(uint*)(Zb + (size_t)(k0 + i) * FF + 2 * l) = *(uint*)&hh; }

__global__ __launch_bounds__(256) void agg_kernel(
    const ushort* __restrict__ Xb, const int* __restrict__ head,
    const int4* __restrict__ rec, ushort* __restrict__ Zb)
{
    const int k0 = ((blockIdx.x * 256 + threadIdx.x) >> 6) * 4;
    const int l = threadIdx.x & 63;

    float ax0 = 0.f, ay0 = 0.f, ax1 = 0.f, ay1 = 0.f;
    float ax2 = 0.f, ay2 = 0.f, ax3 = 0.f, ay3 = 0.f;

    const int4 hv = *(const int4*)&head[k0];
    int e0 = hv.x, e1 = hv.y, e2 = hv.z, e3 = hv.w;

    AGG_L1R(0) AGG_L1R(1) AGG_L1R(2) AGG_L1R(3)
    AGG_L1X(0) AGG_L1X(1) AGG_L1X(2) AGG_L1X(3)
    AGG_L2R(0) AGG_L2R(1) AGG_L2R(2) AGG_L2R(3)
    AGG_L1A(0) AGG_L1A(1) AGG_L1A(2) AGG_L1A(3)
    AGG_L2X(0) AGG_L2X(1) AGG_L2X(2) AGG_L2X(3)
    AGG_L2A(0) AGG_L2A(1) AGG_L2A(2) AGG_L2A(3)

    AGG_WALK(e0, r0, ax0, ay0)
    AGG_WALK(e1, r1, ax1, ay1)
    AGG_WALK(e2, r2, ax2, ay2)
    AGG_WALK(e3, r3, ax3, ay3)

    if (hv.x >= 0) AGG_ST(0)
    if (hv.y >= 0) AGG_ST(1)
    if (hv.z >= 0) AGG_ST(2)
    if (hv.w >= 0) AGG_ST(3)
}

// ---------------- pass 2: GEMM, 18-phase stage-2-ahead pipeline ----------------
// Block = 4 waves, wave = one 16-row tile. W planes split into 16KB halves ->
// 18 phases; 3 LDS buffers (48KB) so phase p stages phase p+2's half into the
// third buffer (no WAR with the one being read). A-loads for matrix m+1 issue
// at even phases. The barrier drain at end of each phase is covered by the
// ~400cy MFMA+ds_read burst that ran since the issues -> latency hidden with
// plain __syncthreads (no inline-asm sync). Empty Zb rows masked by VALUE
// (loads stay issued; poisoned data discarded). D: col=c*16+al, row=R0+ag*4+q.

__device__ __forceinline__ void gload_lds16(const uint4* g, uint4* l) {
    __builtin_amdgcn_global_load_lds(
        (const __attribute__((address_space(1))) void*)g,
        (__attribute__((address_space(3))) void*)l, 16, 0, 0);
}

#define STAGE(q) { \
        const uint4* Ws = Wf4 + ((q) >> 1) * 2048 + ((q) & 1) * 1024 + wid * 64 + l; \
        uint4* lb = &bsh[((q) % 3) * 1024 + wid * 64]; \
        _Pragma("unroll") \
        for (int k = 0; k < 4; ++k) \
            gload_lds16(Ws + k * 256, lb + k * 256); }

#define LOAD_A(AF, P)                                                        \
    _Pragma("unroll")                                                        \
    for (int s = 0; s < 4; ++s)                                              \
        AF[s] = *(const bf16x8*)((P) + s * 32 + ag * 8);

// unconditional loads (uniform shape), value-masked afterwards
#define LOAD_A_V(AF, P, NZ)                                                  \
    _Pragma("unroll")                                                        \
    for (int s = 0; s < 4; ++s) {                                            \
        bf16x8 tv = *(const bf16x8*)((P) + s * 32 + ag * 8);                 \
        AF[s] = (NZ) ? tv : zfrag;                                           \
    }

#define HBURST(AF, p)                                                        \
    _Pragma("unroll")                                                        \
    for (int cl = 0; cl < 4; ++cl) {                                         \
        _Pragma("unroll")                                                    \
        for (int s = 0; s < 4; ++s) {                                        \
            bf16x8 bfr = *(const bf16x8*)&bsh[((p) % 3) * 1024 +             \
                                              (cl * 4 + s) * 64 + l];        \
            acc[((p) & 1) * 4 + cl] = __builtin_amdgcn_mfma_f32_16x16x32_bf16( \
                AF[s], bfr, acc[((p) & 1) * 4 + cl], 0, 0, 0);               \
        }                                                                    \
    }

__global__ __launch_bounds__(256, 3) void gemm_kernel(
    const ushort* __restrict__ Xb, const ushort* __restrict__ Zb,
    const ushort* __restrict__ Wf, const int* __restrict__ head,
    const float* __restrict__ bias, float* __restrict__ out)
{
    __shared__ uint4 bsh[3 * 1024];             // 48 KB: 3 half-plane buffers
    const int t = threadIdx.x;
    const int wid = t >> 6;
    const int l = t & 63;
    const int gw0 = blockIdx.x * 4 + wid;
    const int gwid = (gw0 < NN / 16) ? gw0 : NN / 16 - 1;  // dup tail, benign
    const int R0 = gwid * 16;
    const int al = l & 15;
    const int ag = l >> 4;
    const int arow = R0 + al;                   // this lane's A row

    const uint4* Wf4 = (const uint4*)Wf;
    const bf16x8 zfrag = {0, 0, 0, 0, 0, 0, 0, 0};

    f32x4 acc[8];
    #pragma unroll
    for (int c = 0; c < 8; ++c) acc[c] = (f32x4){0.f, 0.f, 0.f, 0.f};

    // preload all 8 empty-row flags (independent gathers, latencies overlap)
    uint nzmask = 0;
    #pragma unroll
    for (int mm = 0; mm < 8; ++mm)
        if (head[(size_t)mm * NN + arow] >= 0) nzmask |= (1u << mm);

    bf16x8 aA[4], aB[4];
    LOAD_A(aA, Xb + (size_t)arow * FF)          // matrix 0 (Xb)
    STAGE(0)
    STAGE(1)
    __syncthreads();                            // drains prologue stages + A0

    #pragma unroll
    for (int p = 0; p < 18; ++p) {
        if (p < 16) STAGE(p + 2)                // DMA for phase p+2 (3rd buf)
        if ((p & 1) == 0 && (p >> 1) < 8) {     // A for matrix (p>>1)+1
            const int mz = p >> 1;              // Zb plane index
            const ushort* An = Zb + ((size_t)mz * NN + arow) * FF;
            const bool nz = (nzmask >> mz) & 1;
            if ((mz & 1) == 0) { LOAD_A_V(aB, An, nz) }
            else               { LOAD_A_V(aA, An, nz) }
        }
        if (((p >> 1) & 1) == 0) { HBURST(aA, p) } else { HBURST(aB, p) }
        if (p < 17) __syncthreads();            // drain covered by the burst
    }

    #pragma unroll
    for (int c = 0; c < 8; ++c) {
        int col = c * 16 + al;
        float b = bias[col];
        #pragma unroll
        for (int q = 0; q < 4; ++q) {
            int row = R0 + ag * 4 + q;
            out[(size_t)row * UU + col] = fmaxf(acc[c][q] + b, 0.f);
        }
    }
}

// ---------------- launch ----------------

extern "C" void kernel_launch(void* const* d_in, const int* in_sizes, int n_in,
                              void* d_out, int out_size, void* d_ws, size_t ws_size,
                              hipStream_t stream) {
    const float* X     = (const float*)d_in[0];
    const int*   esrc  = (const int*)d_in[1];
    const int*   edst  = (const int*)d_in[2];
    const float* ew    = (const float*)d_in[3];
    const float* Wself = (const float*)d_in[4];
    const float* Wrel  = (const float*)d_in[5];
    const float* bias  = (const float*)d_in[6];
    float* out = (float*)d_out;

    // ws layout (16B-aligned segments), ~125 MB total
    ushort* Zb   = (ushort*)d_ws;               // NKEY*FF bf16 = 102.4 MB
    ushort* Xb   = Zb + (size_t)NKEY * FF;      // NN*FF bf16   = 12.8 MB
    ushort* Wf   = Xb + (size_t)NN * FF;        // 9*FF*UU bf16 = 0.29 MB
    int*    head = (int*)(Wf + 9 * FF * UU);    // NKEY         = 1.6 MB
    int4*   rec  = (int4*)(head + NKEY);        // NET int4     = 7.7 MB

    hipMemsetAsync(head, 0xFF, NKEY * sizeof(int), stream);   // head = -1
    hipLaunchKernelGGL(prepbuild_kernel, dim3(NN * FF / 4 / 256), dim3(256), 0, stream,
                       X, Wself, Wrel, esrc, edst, ew, Xb, Wf, head, rec);
    hipLaunchKernelGGL(agg_kernel,  dim3(NKEY / 16), dim3(256), 0, stream,
                       Xb, head, rec, Zb);
    hipLaunchKernelGGL(gemm_kernel, dim3((NN / 16 + 3) / 4), dim3(256), 0, stream,
                       Xb, Zb, Wf, head, bias, out);
}

// Round 19
// 116.465 us; speedup vs baseline: 1.0898x; 1.0898x over previous
//
#include <hip/hip_runtime.h>
#include <hip/hip_bf16.h>

#define NN 50000
#define FF 128
#define UU 128
#define NREL 8
#define NE 60000
#define NKEY (NREL * NN)        // 400000
#define NET (NREL * NE)         // 480000

typedef __attribute__((ext_vector_type(8))) short bf16x8;
typedef __attribute__((ext_vector_type(4))) float f32x4;

// ---------------- fused prep + build ----------------
// prep: X->bf16; W->fragment layout (for (m,c,s), a 1KB block at
// ((m*8+c)*4+s)*512 ushorts; lane (ag*16+al) holds 8 bf16 of
// W_m[k=s*32+ag*8+j][col=c*16+al]).
// build: per-(rel,dst) linked list via atomicExch (head pre-set to -1 by the
// stream-ordered memset); rec[i] = {src, w_bits, prev, pad}.

__global__ __launch_bounds__(256) void prepbuild_kernel(
    const float* __restrict__ X, const float* __restrict__ Wself,
    const float* __restrict__ Wrel, const int* __restrict__ esrc,
    const int* __restrict__ edst, const float* __restrict__ ew,
    ushort* __restrict__ Xb, ushort* __restrict__ Wf,
    int* __restrict__ head, int4* __restrict__ rec)
{
    int i = blockIdx.x * 256 + threadIdx.x;
    if (i < NN * FF / 4) {                      // X -> bf16
        float4 v = ((const float4*)X)[i];
        union { __hip_bfloat162 h[2]; uint2 u; } p;
        p.h[0] = __float22bfloat162_rn(make_float2(v.x, v.y));
        p.h[1] = __float22bfloat162_rn(make_float2(v.z, v.w));
        ((uint2*)Xb)[i] = p.u;
    }
    if (i < NET) {                              // linked-list build
        int key = (i / NE) * NN + edst[i];      // const divisor -> magic mul
        int prev = atomicExch(&head[key], i);
        rec[i] = make_int4(esrc[i], __float_as_int(ew[i]), prev, 0);
    }
    if (i < 9 * FF * UU) {                      // W -> fragment layout
        int m = i >> 14, k = (i >> 7) & 127, col = i & 127;
        int c = col >> 4, al = col & 15;
        int s = k >> 5, ag = (k >> 3) & 3, j = k & 7;
        float v = (m == 0) ? Wself[i] : Wrel[i - FF * UU];
        __hip_bfloat16 h = __float2bfloat16(v);
        Wf[((m * 8 + c) * 4 + s) * 512 + (ag * 16 + al) * 8 + j] = *(ushort*)&h;
    }
}

// ---------------- pass 1: aggregation (r15 walker + empty-key store skip) -------

#define AGG_L1R(i) int4 r##i = make_int4(0, 0, 0, 0); \
    if (e##i >= 0) r##i = rec[e##i];
#define AGG_L1X(i) uint x##i = 0u; \
    if (e##i >= 0) x##i = *(const uint*)(Xb + (size_t)r##i.x * FF + 2 * l);
#define AGG_L2R(i) int f##i = (e##i >= 0) ? r##i.z : -1; \
    int4 s##i = make_int4(0, 0, 0, 0); \
    if (f##i >= 0) s##i = rec[f##i];
#define AGG_L1A(i) if (e##i >= 0) { \
        float wgt = __int_as_float(r##i.y); \
        ax##i = fmaf(__uint_as_float(x##i << 16), wgt, ax##i); \
        ay##i = fmaf(__uint_as_float(x##i & 0xffff0000u), wgt, ay##i); }
#define AGG_L2X(i) uint y##i = 0u; \
    if (f##i >= 0) y##i = *(const uint*)(Xb + (size_t)s##i.x * FF + 2 * l);
#define AGG_L2A(i) if (f##i >= 0) { \
        float wgt = __int_as_float(s##i.y); \
        ax##i = fmaf(__uint_as_float(y##i << 16), wgt, ax##i); \
        ay##i = fmaf(__uint_as_float(y##i & 0xffff0000u), wgt, ay##i); \
        e##i = s##i.z; \
        if (e##i >= 0) r##i = rec[e##i]; \
    } else e##i = -1;

#define AGG_WALK(e, r, ax, ay)                                              \
    while (e >= 0) {                                                        \
        float w = __int_as_float(r.y);                                      \
        uint x = *(const uint*)(Xb + (size_t)r.x * FF + 2 * l);             \
        e = r.z;                                                            \
        if (e >= 0) r = rec[e];                                             \
        ax = fmaf(__uint_as_float(x << 16), w, ax);                         \
        ay = fmaf(__uint_as_float(x & 0xffff0000u), w, ay);                 \
    }

#define AGG_ST(i) { \
        __hip_bfloat162 hh = __float22bfloat162_rn(make_float2(ax##i, ay##i)); \
        *(uint*)(Zb + (size_t)(k0 + i) * FF + 2 * l) = *(uint*)&hh; }

__global__ __launch_bounds__(256) void agg_kernel(
    const ushort* __restrict__ Xb, const int* __restrict__ head,
    const int4* __restrict__ rec, ushort* __restrict__ Zb)
{
    const int k0 = ((blockIdx.x * 256 + threadIdx.x) >> 6) * 4;
    const int l = threadIdx.x & 63;

    float ax0 = 0.f, ay0 = 0.f, ax1 = 0.f, ay1 = 0.f;
    float ax2 = 0.f, ay2 = 0.f, ax3 = 0.f, ay3 = 0.f;

    const int4 hv = *(const int4*)&head[k0];
    int e0 = hv.x, e1 = hv.y, e2 = hv.z, e3 = hv.w;

    AGG_L1R(0) AGG_L1R(1) AGG_L1R(2) AGG_L1R(3)
    AGG_L1X(0) AGG_L1X(1) AGG_L1X(2) AGG_L1X(3)
    AGG_L2R(0) AGG_L2R(1) AGG_L2R(2) AGG_L2R(3)
    AGG_L1A(0) AGG_L1A(1) AGG_L1A(2) AGG_L1A(3)
    AGG_L2X(0) AGG_L2X(1) AGG_L2X(2) AGG_L2X(3)
    AGG_L2A(0) AGG_L2A(1) AGG_L2A(2) AGG_L2A(3)

    AGG_WALK(e0, r0, ax0, ay0)
    AGG_WALK(e1, r1, ax1, ay1)
    AGG_WALK(e2, r2, ax2, ay2)
    AGG_WALK(e3, r3, ax3, ay3)

    if (hv.x >= 0) AGG_ST(0)
    if (hv.y >= 0) AGG_ST(1)
    if (hv.z >= 0) AGG_ST(2)
    if (hv.w >= 0) AGG_ST(3)
}

// ---------------- pass 2: GEMM, 2-phase double-buffered pipeline ----------------
// Block = 4 waves, wave = one 16-row tile. TWO 32KB LDS buffers: per m, issue
// DMA of W[m+1] into buf[(m+1)&1] and A[m+1] reg loads BEFORE the MFMA burst
// on buf[m&1]; ONE __syncthreads per m (closes DMA-ready for next burst AND
// the WAR on the buffer restaged next iteration). Empty Zb rows skipped via
// preloaded per-lane head flags. D: col=c*16+al, row=R0+ag*4+q.

__device__ __forceinline__ void gload_lds16(const uint4* g, uint4* l) {
    __builtin_amdgcn_global_load_lds(
        (const __attribute__((address_space(1))) void*)g,
        (__attribute__((address_space(3))) void*)l, 16, 0, 0);
}

#define STAGE(mm) { \
        const uint4* Ws = Wf4 + (mm) * 2048 + wid * 64 + l; \
        uint4* lb = &bsh[((mm) & 1) * 2048 + wid * 64]; \
        _Pragma("unroll") \
        for (int k = 0; k < 8; ++k) \
            gload_lds16(Ws + k * 256, lb + k * 256); }

#define LOAD_A(AF, P)                                                        \
    _Pragma("unroll")                                                        \
    for (int s = 0; s < 4; ++s)                                              \
        AF[s] = *(const bf16x8*)((P) + s * 32 + ag * 8);

#define LOAD_A_P(AF, P, NZ)                                                  \
    _Pragma("unroll")                                                        \
    for (int s = 0; s < 4; ++s) AF[s] = zfrag;                               \
    if (NZ) {                                                                \
        _Pragma("unroll")                                                    \
        for (int s = 0; s < 4; ++s)                                          \
            AF[s] = *(const bf16x8*)((P) + s * 32 + ag * 8);                 \
    }

#define MFMA_BURST(AF, mm)                                                   \
    _Pragma("unroll")                                                        \
    for (int c = 0; c < 8; ++c) {                                            \
        _Pragma("unroll")                                                    \
        for (int s = 0; s < 4; ++s) {                                        \
            bf16x8 bfr = *(const bf16x8*)&bsh[((mm) & 1) * 2048 +            \
                                              (c * 4 + s) * 64 + l];         \
            acc[c] = __builtin_amdgcn_mfma_f32_16x16x32_bf16(                \
                AF[s], bfr, acc[c], 0, 0, 0);                                \
        }                                                                    \
    }

__global__ __launch_bounds__(256, 2) void gemm_kernel(
    const ushort* __restrict__ Xb, const ushort* __restrict__ Zb,
    const ushort* __restrict__ Wf, const int* __restrict__ head,
    const float* __restrict__ bias, float* __restrict__ out)
{
    __shared__ uint4 bsh[2 * 2048];             // 64 KB: 2 W-plane buffers
    const int t = threadIdx.x;
    const int wid = t >> 6;
    const int l = t & 63;
    const int gw0 = blockIdx.x * 4 + wid;
    const int gwid = (gw0 < NN / 16) ? gw0 : NN / 16 - 1;  // dup tail, benign
    const int R0 = gwid * 16;
    const int al = l & 15;
    const int ag = l >> 4;
    const int arow = R0 + al;                   // this lane's A row

    const uint4* Wf4 = (const uint4*)Wf;
    const bf16x8 zfrag = {0, 0, 0, 0, 0, 0, 0, 0};

    f32x4 acc[8];
    #pragma unroll
    for (int c = 0; c < 8; ++c) acc[c] = (f32x4){0.f, 0.f, 0.f, 0.f};

    // preload all 8 empty-row flags (independent gathers, latencies overlap)
    uint nzmask = 0;
    #pragma unroll
    for (int mm = 0; mm < 8; ++mm)
        if (head[(size_t)mm * NN + arow] >= 0) nzmask |= (1u << mm);

    bf16x8 aA[4], aB[4];
    LOAD_A(aA, Xb + (size_t)arow * FF)          // matrix 0 (Xb)
    STAGE(0)
    __syncthreads();                            // W[0] + A[0] resident

    #pragma unroll
    for (int m = 0; m < 9; ++m) {
        if (m < 8) {
            STAGE(m + 1)                        // DMA into the OTHER buffer
            const ushort* An = Zb + ((size_t)m * NN + arow) * FF;
            const bool nz = (nzmask >> m) & 1;
            if ((m & 1) == 0) { LOAD_A_P(aB, An, nz) } else { LOAD_A_P(aA, An, nz) }
        }
        if ((m & 1) == 0) { MFMA_BURST(aA, m) } else { MFMA_BURST(aB, m) }
        if (m < 8) __syncthreads();             // drain covered by the burst
    }

    #pragma unroll
    for (int c = 0; c < 8; ++c) {
        int col = c * 16 + al;
        float b = bias[col];
        #pragma unroll
        for (int q = 0; q < 4; ++q) {
            int row = R0 + ag * 4 + q;
            out[(size_t)row * UU + col] = fmaxf(acc[c][q] + b, 0.f);
        }
    }
}

// ---------------- launch ----------------

extern "C" void kernel_launch(void* const* d_in, const int* in_sizes, int n_in,
                              void* d_out, int out_size, void* d_ws, size_t ws_size,
                              hipStream_t stream) {
    const float* X     = (const float*)d_in[0];
    const int*   esrc  = (const int*)d_in[1];
    const int*   edst  = (const int*)d_in[2];
    const float* ew    = (const float*)d_in[3];
    const float* Wself = (const float*)d_in[4];
    const float* Wrel  = (const float*)d_in[5];
    const float* bias  = (const float*)d_in[6];
    float* out = (float*)d_out;

    // ws layout (16B-aligned segments), ~125 MB total
    ushort* Zb   = (ushort*)d_ws;               // NKEY*FF bf16 = 102.4 MB
    ushort* Xb   = Zb + (size_t)NKEY * FF;      // NN*FF bf16   = 12.8 MB
    ushort* Wf   = Xb + (size_t)NN * FF;        // 9*FF*UU bf16 = 0.29 MB
    int*    head = (int*)(Wf + 9 * FF * UU);    // NKEY         = 1.6 MB
    int4*   rec  = (int4*)(head + NKEY);        // NET int4     = 7.7 MB

    hipMemsetAsync(head, 0xFF, NKEY * sizeof(int), stream);   // head = -1
    hipLaunchKernelGGL(prepbuild_kernel, dim3(NN * FF / 4 / 256), dim3(256), 0, stream,
                       X, Wself, Wrel, esrc, edst, ew, Xb, Wf, head, rec);
    hipLaunchKernelGGL(agg_kernel,  dim3(NKEY / 16), dim3(256), 0, stream,
                       Xb, head, rec, Zb);
    hipLaunchKernelGGL(gemm_kernel, dim3((NN / 16 + 3) / 4), dim3(256), 0, stream,
                       Xb, Zb, Wf, head, bias, out);
}